// Round 4
// baseline (166.996 us; speedup 1.0000x reference)
//
#include <hip/hip_runtime.h>
#include <stdint.h>

#define B_  32
#define M_  1024
#define DF  128   // feature dim
#define ED  64    // embedding dim

typedef __attribute__((ext_vector_type(8))) short short8;   // 8 bf16 (4 VGPRs)
typedef __attribute__((ext_vector_type(4))) float floatx4;  // MFMA C/D

__device__ inline unsigned short f2bf(float f) {
    union { float f; unsigned u; } v; v.f = f;
    unsigned r = v.u + 0x7fffu + ((v.u >> 16) & 1u);
    return (unsigned short)(r >> 16);
}

__device__ inline void load_lds16(const void* g, void* l) {
    __builtin_amdgcn_global_load_lds(
        (const __attribute__((address_space(1))) unsigned int*)g,
        (__attribute__((address_space(3))) unsigned int*)l, 16, 0, 0);
}

// ---------------------------------------------------------------- build S + dinv
// S[b][m][n] = bf16(relu(e_m.e_n) + (m==n)) ; dinv[b][m] = rsqrt(rowsum)
// 64-row strip per block over ALL n (complete row sums, no atomics).
// Reads E as fp32 (converts during staging); coalesced 16B S stores via LDS.
__global__ __launch_bounds__(256) void build_s_kernel(
    const float* __restrict__ Ef, unsigned short* __restrict__ S,
    float* __restrict__ dinv) {
    int mt2 = blockIdx.x, b = blockIdx.y;
    int t = threadIdx.x;
    int w = t >> 6, lane = t & 63, quad = lane >> 4, lc = lane & 15;
    __shared__ unsigned short sEn[128][72];       // 18432 B
    __shared__ unsigned short sOut[64 * 136];     // 17408 B
    const float* Eb = Ef + (size_t)b * M_ * ED;
    unsigned short* Sg = S + ((size_t)b << 20);
    int m0 = mt2 * 64;
    int base_m = m0 + w * 16;

    short8 afr[2];                                // rows base_m + lc, fp32 -> bf16
    for (int ks = 0; ks < 2; ++ks) {
        const float* rp = Eb + (size_t)(base_m + lc) * ED + ks * 32 + quad * 8;
        float4 lo = *(const float4*)(rp);
        float4 hi = *(const float4*)(rp + 4);
        short8 v;
        v[0] = f2bf(lo.x); v[1] = f2bf(lo.y); v[2] = f2bf(lo.z); v[3] = f2bf(lo.w);
        v[4] = f2bf(hi.x); v[5] = f2bf(hi.y); v[6] = f2bf(hi.z); v[7] = f2bf(hi.w);
        afr[ks] = v;
    }
    floatx4 rsum = (floatx4){0.f, 0.f, 0.f, 0.f};

    for (int nc = 0; nc < 8; ++nc) {
        __syncthreads();
        // stage 128 x 64 E-chunk, fp32 -> bf16: 2048 float4 -> 8 rounds
        for (int it = 0; it < 8; ++it) {
            int c = t + 256 * it;
            int row = c >> 4, off4 = (c & 15) * 4;
            float4 v = *(const float4*)(Eb + (size_t)(nc * 128 + row) * ED + off4);
            ushort4 o;
            o.x = f2bf(v.x); o.y = f2bf(v.y); o.z = f2bf(v.z); o.w = f2bf(v.w);
            *(ushort4*)(&sEn[row][off4]) = o;
        }
        __syncthreads();
        for (int nt = 0; nt < 8; ++nt) {
            short8 b0 = *(const short8*)(&sEn[nt * 16 + lc][quad * 8]);
            short8 b1 = *(const short8*)(&sEn[nt * 16 + lc][32 + quad * 8]);
            floatx4 s = (floatx4){0.f, 0.f, 0.f, 0.f};
            s = __builtin_amdgcn_mfma_f32_16x16x32_bf16(afr[0], b0, s, 0, 0, 0);
            s = __builtin_amdgcn_mfma_f32_16x16x32_bf16(afr[1], b1, s, 0, 0, 0);
            int n = nc * 128 + nt * 16 + lc;
            for (int r = 0; r < 4; ++r) {
                int m = base_m + quad * 4 + r;
                float v = fmaxf(s[r], 0.f);
                if (m == n) v += 1.0f;
                rsum[r] += v;
                sOut[(w * 16 + quad * 4 + r) * 136 + nt * 16 + lc] = f2bf(v);
            }
        }
        __syncthreads();
        // coalesced store: 64 rows x 128 n = 1024 short8 -> 4 rounds
        for (int it = 0; it < 4; ++it) {
            int c = t + 256 * it;
            int lrow = c >> 4, noff = (c & 15) * 8;
            *(short8*)(Sg + (size_t)(m0 + lrow) * M_ + nc * 128 + noff) =
                *(const short8*)(&sOut[lrow * 136 + noff]);
        }
    }
    for (int r = 0; r < 4; ++r) {
        float v = rsum[r];
        v += __shfl_xor(v, 1, 16);
        v += __shfl_xor(v, 2, 16);
        v += __shfl_xor(v, 4, 16);
        v += __shfl_xor(v, 8, 16);
        if (lc == 0)
            dinv[b * M_ + base_m + quad * 4 + r] = rsqrtf(v);
    }
}

// ---------------------------------------------------------------- Xt = (dinv_n * X)^T (bf16), 64-row tiles
__global__ __launch_bounds__(256) void tscale_kernel(
    const float* __restrict__ X, const float* __restrict__ dinv,
    unsigned short* __restrict__ Xt) {
    int nt = blockIdx.x, b = blockIdx.y;
    int t = threadIdx.x;
    __shared__ unsigned short sT[128][72];
    int nloc = t >> 5;
    int d4 = (t & 31) * 4;
    for (int pass = 0; pass < 8; ++pass) {
        int n = pass * 8 + nloc;
        int grow = b * M_ + nt * 64 + n;
        float sc = dinv[grow];
        float4 v = *(const float4*)(X + (size_t)grow * DF + d4);
        sT[d4 + 0][n] = f2bf(v.x * sc);
        sT[d4 + 1][n] = f2bf(v.y * sc);
        sT[d4 + 2][n] = f2bf(v.z * sc);
        sT[d4 + 3][n] = f2bf(v.w * sc);
    }
    __syncthreads();
    for (int it = 0; it < 4; ++it) {
        int c = t + 256 * it;
        int d = c >> 3, off = (c & 7) * 8;
        *(short8*)(Xt + (size_t)(b * DF + d) * M_ + nt * 64 + off) =
            *(const short8*)(&sT[d][off]);
    }
}

// ---------------------------------------------------------------- GEMM layer, wave-split-K
// Block: 64 m x 128 d, BK=64. Wave (kh,dh): 64m x 64d(half) x 32k -> m97 read:MFMA ratio.
// Z[m][d] = sum_n S[m][n]*Pt[d][n]; Y = dinv_m*Z; H = relu(Y @ W^T) (W read fp32).
// MODE 1: OutT[b][o][m] = bf16(dinv_m * H);  MODE 2: OutF[m][o] = fp32(H)
template <int MODE>
__global__ __launch_bounds__(256) void gemm_kernel(
    const unsigned short* __restrict__ S,
    const unsigned short* __restrict__ Pt,
    const float* __restrict__ Wf,
    const float* __restrict__ dinv,
    unsigned short* __restrict__ OutT,
    float* __restrict__ OutF) {
    int bx = blockIdx.x, b = blockIdx.y;
    int m0 = bx * 64;
    int t = threadIdx.x;
    int w = t >> 6, lane = t & 63, quad = lane >> 4, lc = lane & 15;
    int kh = w >> 1, dh = w & 1;      // K-half, d-half

    __shared__ __align__(16) char lds[52224];
    unsigned short* sA = (unsigned short*)lds;            //  64x64 u16 =  8192 B
    unsigned short* sB = (unsigned short*)(lds + 8192);   // 128x64 u16 = 16384 B
    float* sRed = (float*)lds;                            //  64x128 f32 = 32768 B
    unsigned short* sY = (unsigned short*)lds;            //  64x136 u16 = 17408 B
    unsigned short* sW = (unsigned short*)(lds + 17408);  // 128x136 u16 = 34816 B
    unsigned short* sT = (unsigned short*)lds;            // 128x72 u16 = 18432 B

    const unsigned short* Sg = S + ((size_t)b << 20);
    const unsigned short* Pb = Pt + (size_t)b * DF * M_;

    floatx4 acc[4][4];
    for (int i = 0; i < 4; ++i)
        for (int j = 0; j < 4; ++j) acc[i][j] = (floatx4){0.f, 0.f, 0.f, 0.f};

    for (int nc = 0; nc < 16; ++nc) {
        __syncthreads();
        // sA: 64 x 64 u16 = 512 x 16B -> 2 rounds
        for (int r = 0; r < 2; ++r) {
            int c = r * 256 + w * 64 + lane;
            const void* gp = Sg + (size_t)(m0 + (c >> 3)) * M_ + nc * 64 + (c & 7) * 8;
            load_lds16(gp, (char*)sA + c * 16);
        }
        // sB: 128 x 64 u16 = 1024 x 16B -> 4 rounds
        for (int r = 0; r < 4; ++r) {
            int c = r * 256 + w * 64 + lane;
            const void* gp = Pb + (size_t)(c >> 3) * M_ + nc * 64 + (c & 7) * 8;
            load_lds16(gp, (char*)sB + c * 16);
        }
        __syncthreads();
        short8 afr[4], bfr[4];
        for (int i = 0; i < 4; ++i)
            afr[i] = *(const short8*)(&sA[(i * 16 + lc) * 64 + kh * 32 + quad * 8]);
        for (int j = 0; j < 4; ++j)
            bfr[j] = *(const short8*)(&sB[(dh * 64 + j * 16 + lc) * 64 + kh * 32 + quad * 8]);
        for (int i = 0; i < 4; ++i)
            for (int j = 0; j < 4; ++j)
                acc[i][j] = __builtin_amdgcn_mfma_f32_16x16x32_bf16(afr[i], bfr[j], acc[i][j], 0, 0, 0);
    }

    // ---- cross-wave K reduction (kh=1 -> kh=0)
    __syncthreads();                              // (1) main-loop LDS reads done
    if (kh == 1)
        for (int i = 0; i < 4; ++i)
            for (int j = 0; j < 4; ++j)
                for (int r = 0; r < 4; ++r)
                    sRed[(i * 16 + quad * 4 + r) * 128 + dh * 64 + j * 16 + lc] = acc[i][j][r];
    __syncthreads();                              // (2)
    if (kh == 0)
        for (int i = 0; i < 4; ++i)
            for (int j = 0; j < 4; ++j)
                for (int r = 0; r < 4; ++r)
                    acc[i][j][r] += sRed[(i * 16 + quad * 4 + r) * 128 + dh * 64 + j * 16 + lc];
    float dv[4][4];
    for (int i = 0; i < 4; ++i)
        for (int r = 0; r < 4; ++r)
            dv[i][r] = dinv[b * M_ + m0 + i * 16 + quad * 4 + r];
    __syncthreads();                              // (3) sRed reads done
    if (kh == 0)
        for (int i = 0; i < 4; ++i)
            for (int j = 0; j < 4; ++j)
                for (int r = 0; r < 4; ++r)
                    sY[(i * 16 + quad * 4 + r) * 136 + dh * 64 + j * 16 + lc] =
                        f2bf(acc[i][j][r] * dv[i][r]);
    // stage W fp32 -> bf16: 128x128 -> 2048 short8 -> 8 rounds
    for (int it = 0; it < 8; ++it) {
        int c = t + 256 * it;
        int row = c >> 4, off = (c & 15) * 8;
        const float* wp = Wf + row * DF + off;
        float4 lo = *(const float4*)(wp);
        float4 hi = *(const float4*)(wp + 4);
        short8 v;
        v[0] = f2bf(lo.x); v[1] = f2bf(lo.y); v[2] = f2bf(lo.z); v[3] = f2bf(lo.w);
        v[4] = f2bf(hi.x); v[5] = f2bf(hi.y); v[6] = f2bf(hi.z); v[7] = f2bf(hi.w);
        *(short8*)(&sW[row * 136 + off]) = v;
    }
    __syncthreads();                              // (4)
    // H-GEMM: wave (kh,oh=dh): 64m x 64o x 64k-half
    floatx4 accH[4][4];
    for (int i = 0; i < 4; ++i)
        for (int j = 0; j < 4; ++j) accH[i][j] = (floatx4){0.f, 0.f, 0.f, 0.f};
    for (int ks2 = 0; ks2 < 2; ++ks2) {
        short8 afr[4], bfr[4];
        for (int i = 0; i < 4; ++i)
            afr[i] = *(const short8*)(&sY[(i * 16 + lc) * 136 + kh * 64 + ks2 * 32 + quad * 8]);
        for (int j = 0; j < 4; ++j)
            bfr[j] = *(const short8*)(&sW[(dh * 64 + j * 16 + lc) * 136 + kh * 64 + ks2 * 32 + quad * 8]);
        for (int i = 0; i < 4; ++i)
            for (int j = 0; j < 4; ++j)
                accH[i][j] = __builtin_amdgcn_mfma_f32_16x16x32_bf16(afr[i], bfr[j], accH[i][j], 0, 0, 0);
    }
    __syncthreads();                              // (5) sY/sW reads done
    if (kh == 1)
        for (int i = 0; i < 4; ++i)
            for (int j = 0; j < 4; ++j)
                for (int r = 0; r < 4; ++r)
                    sRed[(i * 16 + quad * 4 + r) * 128 + dh * 64 + j * 16 + lc] = accH[i][j][r];
    __syncthreads();                              // (6)
    if (kh == 0)
        for (int i = 0; i < 4; ++i)
            for (int j = 0; j < 4; ++j)
                for (int r = 0; r < 4; ++r)
                    accH[i][j][r] += sRed[(i * 16 + quad * 4 + r) * 128 + dh * 64 + j * 16 + lc];

    if (MODE == 2) {
        if (kh == 0) {
            float* Ob = OutF + ((size_t)b * M_ + m0) * DF;
            for (int i = 0; i < 4; ++i)
                for (int j = 0; j < 4; ++j) {
                    int mrow = i * 16 + quad * 4;
                    int col = dh * 64 + j * 16 + lc;
                    for (int r = 0; r < 4; ++r)
                        Ob[(size_t)(mrow + r) * DF + col] = fmaxf(accH[i][j][r], 0.f);
                }
        }
    } else {
        __syncthreads();                          // (7) sRed reads done
        if (kh == 0)
            for (int i = 0; i < 4; ++i)
                for (int j = 0; j < 4; ++j) {
                    int col = dh * 64 + j * 16 + lc;
                    for (int r = 0; r < 4; ++r)
                        sT[col * 72 + i * 16 + quad * 4 + r] =
                            f2bf(fmaxf(accH[i][j][r], 0.f) * dv[i][r]);
                }
        __syncthreads();                          // (8)
        // OutT: 128 o x 64 m = 1024 short8 -> 4 rounds
        for (int it = 0; it < 4; ++it) {
            int c = t + 256 * it;
            int o = c >> 3, moff = (c & 7) * 8;
            *(short8*)(OutT + (size_t)(b * DF + o) * M_ + m0 + moff) =
                *(const short8*)(&sT[o * 72 + moff]);
        }
    }
}

// ---------------------------------------------------------------- launch
extern "C" void kernel_launch(void* const* d_in, const int* in_sizes, int n_in,
                              void* d_out, int out_size, void* d_ws, size_t ws_size,
                              hipStream_t stream) {
    (void)in_sizes; (void)n_in; (void)out_size; (void)ws_size;
    const float* X  = (const float*)d_in[0];   // (B*M, 128)
    const float* E  = (const float*)d_in[1];   // (B*M, 64)
    const float* W1 = (const float*)d_in[2];   // (128, 128)
    const float* W2 = (const float*)d_in[3];   // (128, 128)
    float* out = (float*)d_out;

    char* ws = (char*)d_ws;                    // ~84 MB of >=268 MB
    float*          dinv = (float*)(ws);                    // 131072 B
    unsigned short* Xt   = (unsigned short*)(ws + 131072);  // 8 MB
    unsigned short* Ht   = (unsigned short*)(ws + 8519680); // 8 MB
    unsigned short* Smat = (unsigned short*)(ws + 16908288);// 64 MB

    build_s_kernel<<<dim3(16, 32), 256, 0, stream>>>(E, Smat, dinv);
    tscale_kernel<<<dim3(16, 32), 256, 0, stream>>>(X, dinv, Xt);
    gemm_kernel<1><<<dim3(16, 32), 256, 0, stream>>>(Smat, Xt, W1, dinv, Ht, nullptr);
    gemm_kernel<2><<<dim3(16, 32), 256, 0, stream>>>(Smat, Ht, W2, dinv, nullptr, out);
}